// Round 4
// baseline (120.873 us; speedup 1.0000x reference)
//
#include <hip/hip_runtime.h>
#include <hip/hip_bf16.h>
#include <math.h>

constexpr int B = 4, C = 64, H = 128, W = 128, K = 9, O = 64;
constexpr int HXW = H * W;
constexpr int C4 = C / 4;

typedef short short8 __attribute__((ext_vector_type(8)));
typedef float f32x4 __attribute__((ext_vector_type(4)));

static __device__ __forceinline__ short f2bf(float v) {
    __hip_bfloat16 h = __float2bfloat16(v);
    return (short)__builtin_bit_cast(unsigned short, h);
}

// weight[O][C][K] -> wt[K][C][O]  (fp32, fallback path only)
__global__ void wt_kernel(const float* __restrict__ weight, float* __restrict__ wt) {
    int idx = blockIdx.x * 256 + threadIdx.x;
    if (idx >= K * C * O) return;
    int o = idx & 63;
    int c = (idx >> 6) & 63;
    int k = idx >> 12;
    wt[idx] = weight[(o * C + c) * K + k];
}

// Fused prep: blocks [0,1024) do x NCHW -> xq NC/4HW4 (4x4 transpose, all float4);
// blocks [1024, 1024+144) do weight[O][C][K] -> wtb[K][O][C] bf16.
constexpr int XQ4_BLOCKS = B * C4 * (HXW / 4) / 256;   // 1024
__global__ void prep_kernel(const float* __restrict__ x, const float* __restrict__ weight,
                            float4* __restrict__ xq, short* __restrict__ wtb) {
    int bid = blockIdx.x;
    if (bid < XQ4_BLOCKS) {
        int idx = bid * 256 + threadIdx.x;     // (b, c4, hwg): 4*16*4096
        int hwg = idx & 4095;
        int t = idx >> 12;
        int c4 = t & 15;
        int b = t >> 4;
        int hw = hwg * 4;
        const float* src = x + ((size_t)(b * C + c4 * 4)) * HXW + hw;
        float4 v0 = *(const float4*)(src);
        float4 v1 = *(const float4*)(src + HXW);
        float4 v2 = *(const float4*)(src + 2 * HXW);
        float4 v3 = *(const float4*)(src + 3 * HXW);
        float4* dst = xq + ((size_t)(b * C4 + c4)) * HXW + hw;
        dst[0] = make_float4(v0.x, v1.x, v2.x, v3.x);
        dst[1] = make_float4(v0.y, v1.y, v2.y, v3.y);
        dst[2] = make_float4(v0.z, v1.z, v2.z, v3.z);
        dst[3] = make_float4(v0.w, v1.w, v2.w, v3.w);
    } else {
        int idx = (bid - XQ4_BLOCKS) * 256 + threadIdx.x;
        if (idx < K * O * C) {
            int c = idx & 63;
            int o = (idx >> 6) & 63;
            int k = idx >> 12;
            wtb[idx] = f2bf(weight[(o * C + c) * K + k]);
        }
    }
}

// 1024 blocks x 256 threads. Block = 64 pixels; 4 waves x (16 px, 64 out).
// slab = bid & 7 -> (batch, half-image) so each XCD's gathers stay in its L2.
__global__ __launch_bounds__(256, 4) void mdcn_mfma(
        const float4* __restrict__ xq,     // [B][C4][H][W] float4
        const float* __restrict__ offset,  // [B][2K][H][W]
        const float* __restrict__ mask,    // [B][K][H][W]
        const short* __restrict__ wtb,     // [K][O][C] bf16
        const float* __restrict__ bias,    // [O]
        float* __restrict__ out) {         // [B][O][H][W]
    __shared__ short A[2][64 * 64];        // 2 x 8 KB, XOR-swizzled 16B slots

    int bid = blockIdx.x;
    int slab = bid & 7;
    int within = bid >> 3;                  // 0..127
    int tid = threadIdx.x;
    int p = tid >> 2;                       // block-local pixel 0..63
    int q = tid & 3;                        // channel quarter (16 ch)
    int pid = slab * 8192 + within * 64 + p;
    int b = slab >> 1;
    int hw = pid & (HXW - 1);
    int h = hw >> 7;
    int w = hw & 127;

    int lane = tid & 63;
    int wid = tid >> 6;                     // wave id 0..3 -> px [wid*16, +16)
    int ml = lane & 15;
    int kg = lane >> 4;

    f32x4 acc[4];
#pragma unroll
    for (int nf = 0; nf < 4; ++nf) {
        float bv = bias[nf * 16 + ml];
        acc[nf] = (f32x4){bv, bv, bv, bv};
    }

    size_t xbase = (size_t)b * C4 * HXW;    // float4 units

#pragma unroll 1
    for (int k = 0; k < K; ++k) {
        // ---- sampling: this thread does pixel p, channels [q*16, q*16+16)
        float offy = offset[((size_t)(b * 2 * K + 2 * k)) * HXW + hw];
        float offx = offset[((size_t)(b * 2 * K + 2 * k + 1)) * HXW + hw];
        float m    = mask[((size_t)(b * K + k)) * HXW + hw];

        float sy = (float)(h - 1 + k / 3) + offy;
        float sx = (float)(w - 1 + k % 3) + offx;
        float y0f = floorf(sy), x0f = floorf(sx);
        float wy = sy - y0f, wx = sx - x0f;
        int y0 = (int)y0f, x0 = (int)x0f;
        int y1 = y0 + 1, x1 = x0 + 1;
        bool vy0 = (y0 >= 0) & (y0 < H), vy1 = (y1 >= 0) & (y1 < H);
        bool vx0 = (x0 >= 0) & (x0 < W), vx1 = (x1 >= 0) & (x1 < W);
        float w00 = (vy0 & vx0) ? (1.0f - wy) * (1.0f - wx) * m : 0.0f;
        float w01 = (vy0 & vx1) ? (1.0f - wy) * wx * m : 0.0f;
        float w10 = (vy1 & vx0) ? wy * (1.0f - wx) * m : 0.0f;
        float w11 = (vy1 & vx1) ? wy * wx * m : 0.0f;
        int y0c = min(max(y0, 0), H - 1), y1c = min(max(y1, 0), H - 1);
        int x0c = min(max(x0, 0), W - 1), x1c = min(max(x1, 0), W - 1);
        int p00 = y0c * W + x0c, p01 = y0c * W + x1c;
        int p10 = y1c * W + x0c, p11 = y1c * W + x1c;

        // issue ALL 16 corner loads back-to-back (max VMEM in flight)
        float4 r[4][4];
#pragma unroll
        for (int g = 0; g < 4; ++g) {
            size_t cs = xbase + (size_t)(q * 4 + g) * HXW;
            r[g][0] = xq[cs + p00];
            r[g][1] = xq[cs + p01];
            r[g][2] = xq[cs + p10];
            r[g][3] = xq[cs + p11];
        }

        short* Ab = &A[k & 1][0];
#pragma unroll
        for (int j = 0; j < 2; ++j) {       // j = 8-channel group within this quarter
            short8 pk;
#pragma unroll
            for (int jj = 0; jj < 2; ++jj) {
                int g = j * 2 + jj;
                pk[jj * 4 + 0] = f2bf(w00 * r[g][0].x + w01 * r[g][1].x + w10 * r[g][2].x + w11 * r[g][3].x);
                pk[jj * 4 + 1] = f2bf(w00 * r[g][0].y + w01 * r[g][1].y + w10 * r[g][2].y + w11 * r[g][3].y);
                pk[jj * 4 + 2] = f2bf(w00 * r[g][0].z + w01 * r[g][1].z + w10 * r[g][2].z + w11 * r[g][3].z);
                pk[jj * 4 + 3] = f2bf(w00 * r[g][0].w + w01 * r[g][1].w + w10 * r[g][2].w + w11 * r[g][3].w);
            }
            int slot = q * 2 + j;
            *(short8*)(Ab + p * 64 + ((slot ^ (p & 7)) << 3)) = pk;
        }

        __syncthreads();

        // ---- B fragments (loaded after barrier: keeps sampling reg pressure low)
        short8 bf[2][4];
#pragma unroll
        for (int ks = 0; ks < 2; ++ks)
#pragma unroll
            for (int nf = 0; nf < 4; ++nf)
                bf[ks][nf] = *(const short8*)(wtb + ((k * O + nf * 16 + ml) * C + ks * 32 + kg * 8));

        // ---- MFMA: wave `wid` computes px [wid*16, +16) x all 64 outputs
        short8 af[2];
#pragma unroll
        for (int ks = 0; ks < 2; ++ks) {
            int px = wid * 16 + ml;
            int slot = ks * 4 + kg;
            af[ks] = *(const short8*)(Ab + px * 64 + ((slot ^ (px & 7)) << 3));
        }
#pragma unroll
        for (int ks = 0; ks < 2; ++ks)
#pragma unroll
            for (int nf = 0; nf < 4; ++nf)
                acc[nf] = __builtin_amdgcn_mfma_f32_16x16x32_bf16(af[ks], bf[ks][nf], acc[nf], 0, 0, 0);
        // no second barrier: next tap writes the OTHER LDS buffer
    }

    // ---- store: D row(px) = (lane>>4)*4+reg, col(o) = lane&15
    int hwb = (slab & 1) * 8192 + within * 64 + wid * 16;
#pragma unroll
    for (int nf = 0; nf < 4; ++nf) {
        size_t ob = ((size_t)(b * O + nf * 16 + ml)) * HXW + hwb + kg * 4;
        *(float4*)(out + ob) = __builtin_bit_cast(float4, acc[nf]);
    }
}

// Fallback (ws too small): direct NCHW fp32 (proven in round 1).
__global__ __launch_bounds__(256) void mdcn_nchw(
        const float* __restrict__ x, const float* __restrict__ offset,
        const float* __restrict__ mask, const float* __restrict__ wt,
        const float* __restrict__ bias, float* __restrict__ out) {
    int pid = blockIdx.x * 256 + threadIdx.x;
    int b = pid >> 14;
    int hw = pid & (HXW - 1);
    int h = hw >> 7;
    int w = hw & 127;
    float acc[O];
#pragma unroll
    for (int o = 0; o < O; ++o) acc[o] = bias[o];
#pragma unroll 1
    for (int k = 0; k < K; ++k) {
        float offy = offset[((size_t)(b * 2 * K + 2 * k)) * HXW + hw];
        float offx = offset[((size_t)(b * 2 * K + 2 * k + 1)) * HXW + hw];
        float m    = mask[((size_t)(b * K + k)) * HXW + hw];
        float sy = (float)(h - 1 + k / 3) + offy;
        float sx = (float)(w - 1 + k % 3) + offx;
        float y0f = floorf(sy), x0f = floorf(sx);
        float wy = sy - y0f, wx = sx - x0f;
        int y0 = (int)y0f, x0 = (int)x0f;
        int y1 = y0 + 1, x1 = x0 + 1;
        bool vy0 = (y0 >= 0) & (y0 < H), vy1 = (y1 >= 0) & (y1 < H);
        bool vx0 = (x0 >= 0) & (x0 < W), vx1 = (x1 >= 0) & (x1 < W);
        float w00 = (vy0 & vx0) ? (1.0f - wy) * (1.0f - wx) * m : 0.0f;
        float w01 = (vy0 & vx1) ? (1.0f - wy) * wx * m : 0.0f;
        float w10 = (vy1 & vx0) ? wy * (1.0f - wx) * m : 0.0f;
        float w11 = (vy1 & vx1) ? wy * wx * m : 0.0f;
        int y0c = min(max(y0, 0), H - 1), y1c = min(max(y1, 0), H - 1);
        int x0c = min(max(x0, 0), W - 1), x1c = min(max(x1, 0), W - 1);
        const float* p00 = x + (size_t)b * C * HXW + y0c * W + x0c;
        const float* p01 = x + (size_t)b * C * HXW + y0c * W + x1c;
        const float* p10 = x + (size_t)b * C * HXW + y1c * W + x0c;
        const float* p11 = x + (size_t)b * C * HXW + y1c * W + x1c;
        const float* wk = wt + k * C * O;
#pragma unroll 1
        for (int c0 = 0; c0 < C; c0 += 4) {
            float v[4];
#pragma unroll
            for (int j = 0; j < 4; ++j) {
                size_t cs = (size_t)(c0 + j) * HXW;
                v[j] = w00 * p00[cs] + w01 * p01[cs] + w10 * p10[cs] + w11 * p11[cs];
            }
            const float* wr = wk + c0 * O;
#pragma unroll
            for (int j = 0; j < 4; ++j)
#pragma unroll
                for (int o = 0; o < O; ++o) acc[o] = fmaf(wr[j * O + o], v[j], acc[o]);
        }
    }
#pragma unroll
    for (int o = 0; o < O; ++o) out[((size_t)(b * O + o)) * HXW + hw] = acc[o];
}

extern "C" void kernel_launch(void* const* d_in, const int* in_sizes, int n_in,
                              void* d_out, int out_size, void* d_ws, size_t ws_size,
                              hipStream_t stream) {
    const float* x      = (const float*)d_in[0];
    const float* offset = (const float*)d_in[1];
    const float* mask   = (const float*)d_in[2];
    const float* weight = (const float*)d_in[3];
    const float* bias   = (const float*)d_in[4];
    float* out = (float*)d_out;

    float* wt   = (float*)d_ws;                                   // 147456 B
    short* wtb  = (short*)((char*)d_ws + 147456);                 // 73728 B
    float4* xq  = (float4*)((char*)d_ws + 147456 + 73728);        // 16.8 MB
    size_t need = 147456 + 73728 + (size_t)B * C4 * HXW * sizeof(float4);

    if (ws_size >= need) {
        int wtb_blocks = (K * O * C + 255) / 256;                 // 144
        prep_kernel<<<XQ4_BLOCKS + wtb_blocks, 256, 0, stream>>>(x, weight, xq, wtb);
        mdcn_mfma<<<1024, 256, 0, stream>>>(xq, offset, mask, wtb, bias, out);
    } else {
        wt_kernel<<<(K * C * O + 255) / 256, 256, 0, stream>>>(weight, wt);
        mdcn_nchw<<<(B * HXW) / 256, 256, 0, stream>>>(x, offset, mask, wt, bias, out);
    }
}

// Round 5
// 103.933 us; speedup vs baseline: 1.1630x; 1.1630x over previous
//
#include <hip/hip_runtime.h>
#include <hip/hip_bf16.h>
#include <math.h>

constexpr int B = 4, C = 64, H = 128, W = 128, K = 9, O = 64;
constexpr int HXW = H * W;

typedef short short8 __attribute__((ext_vector_type(8)));
typedef float f32x4 __attribute__((ext_vector_type(4)));

static __device__ __forceinline__ short f2bf(float v) {
    __hip_bfloat16 h = __float2bfloat16(v);
    return (short)__builtin_bit_cast(unsigned short, h);
}

// Combine 4 corners (2 float4 each = 8 channels) into a bf16 short8 A-fragment.
static __device__ __forceinline__ short8 combine8(
        const float4* a, const float4* b, const float4* c, const float4* d,
        float w00, float w01, float w10, float w11) {
    short8 r;
#pragma unroll
    for (int jj = 0; jj < 2; ++jj) {
        const float* fa = (const float*)&a[jj];
        const float* fb = (const float*)&b[jj];
        const float* fc = (const float*)&c[jj];
        const float* fd = (const float*)&d[jj];
#pragma unroll
        for (int i = 0; i < 4; ++i) {
            float v = w00 * fa[i] + w01 * fb[i] + w10 * fc[i] + w11 * fd[i];
            r[jj * 4 + i] = f2bf(v);
        }
    }
    return r;
}

// weight[O][C][K] -> wt[K][C][O]  (fp32, fallback path only)
__global__ void wt_kernel(const float* __restrict__ weight, float* __restrict__ wt) {
    int idx = blockIdx.x * 256 + threadIdx.x;
    if (idx >= K * C * O) return;
    int o = idx & 63;
    int c = (idx >> 6) & 63;
    int k = idx >> 12;
    wt[idx] = weight[(o * C + c) * K + k];
}

// Prep: blocks [0,512) transpose x NCHW -> xt NHWC fp32 via LDS (pad-65, 2-way free);
// blocks [512, 512+144) do weight[O][C][K] -> wtb[K][O][C] bf16.
constexpr int XT_BLOCKS = B * HXW / 128;   // 512
__global__ __launch_bounds__(256) void prep_kernel(
        const float* __restrict__ x, const float* __restrict__ weight,
        float* __restrict__ xt, short* __restrict__ wtb) {
    int bid = blockIdx.x;
    if (bid < XT_BLOCKS) {
        __shared__ float lds[128 * 65];
        int t = threadIdx.x;
        int P = bid * 128;                  // first pixel of this block
        int b = P >> 14;
        int hw0 = P & (HXW - 1);
        int px = t & 127;
        int hf = t >> 7;                    // 0/1: channel half
        const float* src = x + (size_t)b * C * HXW + hw0 + px;
#pragma unroll
        for (int cc = 0; cc < 32; ++cc) {
            int ch = hf * 32 + cc;
            lds[px * 65 + ch] = src[(size_t)ch * HXW];
        }
        __syncthreads();
        float* dst = xt + ((size_t)b * HXW + hw0 + px) * 64 + hf * 32;
        const float* row = lds + px * 65 + hf * 32;
#pragma unroll
        for (int j = 0; j < 8; ++j) {
            float4 v = make_float4(row[j * 4], row[j * 4 + 1], row[j * 4 + 2], row[j * 4 + 3]);
            *(float4*)(dst + j * 4) = v;
        }
    } else {
        int idx = (bid - XT_BLOCKS) * 256 + threadIdx.x;
        if (idx < K * O * C) {
            int c = idx & 63;
            int o = (idx >> 6) & 63;
            int k = idx >> 12;
            wtb[idx] = f2bf(weight[(o * C + c) * K + k]);
        }
    }
}

// 512 blocks x 256 threads, NO LDS, NO barriers. Block = 128 px (one image row
// chunk); wave = 32 px x 64 out. Lane (ml,kg) samples its own MFMA A-fragment:
// pixel = wid*32 + mf*16 + ml, channels ks*32 + kg*8 .. +8 -> register-direct.
// slab = bid & 7 -> (batch, half-image) keeps each XCD's gathers in its L2.
__global__ __launch_bounds__(256, 2) void mdcn_nhwc(
        const float* __restrict__ xt,      // [B][H][W][64] fp32, 256 B/px
        const float* __restrict__ offset,  // [B][2K][H][W]
        const float* __restrict__ mask,    // [B][K][H][W]
        const short* __restrict__ wtb,     // [K][O][C] bf16
        const float* __restrict__ bias,    // [O]
        float* __restrict__ out) {         // [B][O][H][W]
    int bid = blockIdx.x;
    int slab = bid & 7;
    int within = bid >> 3;                  // 0..63
    int tid = threadIdx.x;
    int lane = tid & 63;
    int wid = tid >> 6;
    int ml = lane & 15;
    int kg = lane >> 4;
    int b = slab >> 1;
    int hwrow = (slab & 1) * 8192 + within * 128 + wid * 32;  // wave's 32-px base
    int h = hwrow >> 7;                     // whole block sits in one image row

    f32x4 acc[2][4];
#pragma unroll
    for (int nf = 0; nf < 4; ++nf) {
        float bv = bias[nf * 16 + ml];
        acc[0][nf] = (f32x4){bv, bv, bv, bv};
        acc[1][nf] = (f32x4){bv, bv, bv, bv};
    }

    const float* xb = xt + (size_t)b * HXW * 64;

#pragma unroll 1
    for (int k = 0; k < K; ++k) {
        // B fragments: wtb[k][o][ch], lane holds o = nf*16+ml, ch = ks*32+kg*8..+8
        short8 bf[2][4];
#pragma unroll
        for (int ks = 0; ks < 2; ++ks)
#pragma unroll
            for (int nf = 0; nf < 4; ++nf)
                bf[ks][nf] = *(const short8*)(wtb + ((k * O + nf * 16 + ml) * C + ks * 32 + kg * 8));

        short8 af[2][2];                    // [mf][ks]
#pragma unroll
        for (int mf = 0; mf < 2; ++mf) {
            int hw = hwrow + mf * 16 + ml;  // this lane's pixel
            int w = hw & 127;

            float offy = offset[((size_t)(b * 2 * K + 2 * k)) * HXW + hw];
            float offx = offset[((size_t)(b * 2 * K + 2 * k + 1)) * HXW + hw];
            float m    = mask[((size_t)(b * K + k)) * HXW + hw];

            float sy = (float)(h - 1 + k / 3) + offy;
            float sx = (float)(w - 1 + k % 3) + offx;
            float y0f = floorf(sy), x0f = floorf(sx);
            float wy = sy - y0f, wx = sx - x0f;
            int y0 = (int)y0f, x0 = (int)x0f;
            int y1 = y0 + 1, x1 = x0 + 1;
            bool vy0 = (y0 >= 0) & (y0 < H), vy1 = (y1 >= 0) & (y1 < H);
            bool vx0 = (x0 >= 0) & (x0 < W), vx1 = (x1 >= 0) & (x1 < W);
            float w00 = (vy0 & vx0) ? (1.0f - wy) * (1.0f - wx) * m : 0.0f;
            float w01 = (vy0 & vx1) ? (1.0f - wy) * wx * m : 0.0f;
            float w10 = (vy1 & vx0) ? wy * (1.0f - wx) * m : 0.0f;
            float w11 = (vy1 & vx1) ? wy * wx * m : 0.0f;
            int y0c = min(max(y0, 0), H - 1), y1c = min(max(y1, 0), H - 1);
            int x0c = min(max(x0, 0), W - 1), x1c = min(max(x1, 0), W - 1);

            // this lane's channel window: ks*128B + kg*32B within the 256-B pixel
            const float* p00 = xb + ((size_t)(y0c * W + x0c) << 6) + kg * 8;
            const float* p01 = xb + ((size_t)(y0c * W + x1c) << 6) + kg * 8;
            const float* p10 = xb + ((size_t)(y1c * W + x0c) << 6) + kg * 8;
            const float* p11 = xb + ((size_t)(y1c * W + x1c) << 6) + kg * 8;

            float4 c00[4], c01[4], c10[4], c11[4];  // [ks*2 + j]
#pragma unroll
            for (int ks = 0; ks < 2; ++ks)
#pragma unroll
                for (int j = 0; j < 2; ++j) {
                    int idx = ks * 2 + j;
                    int off = ks * 32 + j * 4;
                    c00[idx] = *(const float4*)(p00 + off);
                    c01[idx] = *(const float4*)(p01 + off);
                    c10[idx] = *(const float4*)(p10 + off);
                    c11[idx] = *(const float4*)(p11 + off);
                }
#pragma unroll
            for (int ks = 0; ks < 2; ++ks)
                af[mf][ks] = combine8(&c00[ks * 2], &c01[ks * 2], &c10[ks * 2], &c11[ks * 2],
                                      w00, w01, w10, w11);
        }

#pragma unroll
        for (int ks = 0; ks < 2; ++ks)
#pragma unroll
            for (int mf = 0; mf < 2; ++mf)
#pragma unroll
                for (int nf = 0; nf < 4; ++nf)
                    acc[mf][nf] = __builtin_amdgcn_mfma_f32_16x16x32_bf16(
                        af[mf][ks], bf[ks][nf], acc[mf][nf], 0, 0, 0);
    }

    // store: D row(px within 16) = kg*4 + reg, col(o) = nf*16 + ml
#pragma unroll
    for (int mf = 0; mf < 2; ++mf)
#pragma unroll
        for (int nf = 0; nf < 4; ++nf) {
            size_t ob = ((size_t)(b * O + nf * 16 + ml)) * HXW + hwrow + mf * 16 + kg * 4;
            *(float4*)(out + ob) = __builtin_bit_cast(float4, acc[mf][nf]);
        }
}

// Fallback (ws too small): direct NCHW fp32 (proven in round 1).
__global__ __launch_bounds__(256) void mdcn_nchw(
        const float* __restrict__ x, const float* __restrict__ offset,
        const float* __restrict__ mask, const float* __restrict__ wt,
        const float* __restrict__ bias, float* __restrict__ out) {
    int pid = blockIdx.x * 256 + threadIdx.x;
    int b = pid >> 14;
    int hw = pid & (HXW - 1);
    int h = hw >> 7;
    int w = hw & 127;
    float acc[O];
#pragma unroll
    for (int o = 0; o < O; ++o) acc[o] = bias[o];
#pragma unroll 1
    for (int k = 0; k < K; ++k) {
        float offy = offset[((size_t)(b * 2 * K + 2 * k)) * HXW + hw];
        float offx = offset[((size_t)(b * 2 * K + 2 * k + 1)) * HXW + hw];
        float m    = mask[((size_t)(b * K + k)) * HXW + hw];
        float sy = (float)(h - 1 + k / 3) + offy;
        float sx = (float)(w - 1 + k % 3) + offx;
        float y0f = floorf(sy), x0f = floorf(sx);
        float wy = sy - y0f, wx = sx - x0f;
        int y0 = (int)y0f, x0 = (int)x0f;
        int y1 = y0 + 1, x1 = x0 + 1;
        bool vy0 = (y0 >= 0) & (y0 < H), vy1 = (y1 >= 0) & (y1 < H);
        bool vx0 = (x0 >= 0) & (x0 < W), vx1 = (x1 >= 0) & (x1 < W);
        float w00 = (vy0 & vx0) ? (1.0f - wy) * (1.0f - wx) * m : 0.0f;
        float w01 = (vy0 & vx1) ? (1.0f - wy) * wx * m : 0.0f;
        float w10 = (vy1 & vx0) ? wy * (1.0f - wx) * m : 0.0f;
        float w11 = (vy1 & vx1) ? wy * wx * m : 0.0f;
        int y0c = min(max(y0, 0), H - 1), y1c = min(max(y1, 0), H - 1);
        int x0c = min(max(x0, 0), W - 1), x1c = min(max(x1, 0), W - 1);
        const float* p00 = x + (size_t)b * C * HXW + y0c * W + x0c;
        const float* p01 = x + (size_t)b * C * HXW + y0c * W + x1c;
        const float* p10 = x + (size_t)b * C * HXW + y1c * W + x0c;
        const float* p11 = x + (size_t)b * C * HXW + y1c * W + x1c;
        const float* wk = wt + k * C * O;
#pragma unroll 1
        for (int c0 = 0; c0 < C; c0 += 4) {
            float v[4];
#pragma unroll
            for (int j = 0; j < 4; ++j) {
                size_t cs = (size_t)(c0 + j) * HXW;
                v[j] = w00 * p00[cs] + w01 * p01[cs] + w10 * p10[cs] + w11 * p11[cs];
            }
            const float* wr = wk + c0 * O;
#pragma unroll
            for (int j = 0; j < 4; ++j)
#pragma unroll
                for (int o = 0; o < O; ++o) acc[o] = fmaf(wr[j * O + o], v[j], acc[o]);
        }
    }
#pragma unroll
    for (int o = 0; o < O; ++o) out[((size_t)(b * O + o)) * HXW + hw] = acc[o];
}

extern "C" void kernel_launch(void* const* d_in, const int* in_sizes, int n_in,
                              void* d_out, int out_size, void* d_ws, size_t ws_size,
                              hipStream_t stream) {
    const float* x      = (const float*)d_in[0];
    const float* offset = (const float*)d_in[1];
    const float* mask   = (const float*)d_in[2];
    const float* weight = (const float*)d_in[3];
    const float* bias   = (const float*)d_in[4];
    float* out = (float*)d_out;

    float* wt  = (float*)d_ws;                                    // 147456 B (fallback)
    short* wtb = (short*)((char*)d_ws + 147456);                  // 73728 B
    float* xt  = (float*)((char*)d_ws + 147456 + 73728);          // 16.78 MB NHWC
    size_t need = 147456 + 73728 + (size_t)B * HXW * 64 * sizeof(float);

    if (ws_size >= need) {
        int wtb_blocks = (K * O * C + 255) / 256;                 // 144
        prep_kernel<<<XT_BLOCKS + wtb_blocks, 256, 0, stream>>>(x, weight, xt, wtb);
        mdcn_nhwc<<<512, 256, 0, stream>>>(xt, offset, mask, wtb, bias, out);
    } else {
        wt_kernel<<<(K * C * O + 255) / 256, 256, 0, stream>>>(weight, wt);
        mdcn_nchw<<<(B * HXW) / 256, 256, 0, stream>>>(x, offset, mask, wt, bias, out);
    }
}

// Round 6
// 45.586 us; speedup vs baseline: 2.6515x; 2.2799x over previous
//
#include <hip/hip_runtime.h>
#include <hip/hip_bf16.h>
#include <math.h>

constexpr int B = 4, C = 64, H = 128, W = 128, K = 9, O = 64;
constexpr int HXW = H * W;

typedef short short8 __attribute__((ext_vector_type(8)));
typedef float f32x4 __attribute__((ext_vector_type(4)));

static __device__ __forceinline__ short f2bf(float v) {
    __hip_bfloat16 h = __float2bfloat16(v);
    return (short)__builtin_bit_cast(unsigned short, h);
}
static __device__ __forceinline__ float bf2f(short s) {
    unsigned int u = ((unsigned int)(unsigned short)s) << 16;
    return __builtin_bit_cast(float, u);
}

// ---------------- fallback path (fp32, proven round 1) ----------------
__global__ void wt_kernel(const float* __restrict__ weight, float* __restrict__ wt) {
    int idx = blockIdx.x * 256 + threadIdx.x;
    if (idx >= K * C * O) return;
    int o = idx & 63;
    int c = (idx >> 6) & 63;
    int k = idx >> 12;
    wt[idx] = weight[(o * C + c) * K + k];
}

__global__ __launch_bounds__(256) void mdcn_nchw(
        const float* __restrict__ x, const float* __restrict__ offset,
        const float* __restrict__ mask, const float* __restrict__ wt,
        const float* __restrict__ bias, float* __restrict__ out) {
    int pid = blockIdx.x * 256 + threadIdx.x;
    int b = pid >> 14;
    int hw = pid & (HXW - 1);
    int h = hw >> 7;
    int w = hw & 127;
    float acc[O];
#pragma unroll
    for (int o = 0; o < O; ++o) acc[o] = bias[o];
#pragma unroll 1
    for (int k = 0; k < K; ++k) {
        float offy = offset[((size_t)(b * 2 * K + 2 * k)) * HXW + hw];
        float offx = offset[((size_t)(b * 2 * K + 2 * k + 1)) * HXW + hw];
        float m    = mask[((size_t)(b * K + k)) * HXW + hw];
        float sy = (float)(h - 1 + k / 3) + offy;
        float sx = (float)(w - 1 + k % 3) + offx;
        float y0f = floorf(sy), x0f = floorf(sx);
        float wy = sy - y0f, wx = sx - x0f;
        int y0 = (int)y0f, x0 = (int)x0f;
        int y1 = y0 + 1, x1 = x0 + 1;
        bool vy0 = (y0 >= 0) & (y0 < H), vy1 = (y1 >= 0) & (y1 < H);
        bool vx0 = (x0 >= 0) & (x0 < W), vx1 = (x1 >= 0) & (x1 < W);
        float w00 = (vy0 & vx0) ? (1.0f - wy) * (1.0f - wx) * m : 0.0f;
        float w01 = (vy0 & vx1) ? (1.0f - wy) * wx * m : 0.0f;
        float w10 = (vy1 & vx0) ? wy * (1.0f - wx) * m : 0.0f;
        float w11 = (vy1 & vx1) ? wy * wx * m : 0.0f;
        int y0c = min(max(y0, 0), H - 1), y1c = min(max(y1, 0), H - 1);
        int x0c = min(max(x0, 0), W - 1), x1c = min(max(x1, 0), W - 1);
        const float* p00 = x + (size_t)b * C * HXW + y0c * W + x0c;
        const float* p01 = x + (size_t)b * C * HXW + y0c * W + x1c;
        const float* p10 = x + (size_t)b * C * HXW + y1c * W + x0c;
        const float* p11 = x + (size_t)b * C * HXW + y1c * W + x1c;
        const float* wk = wt + k * C * O;
#pragma unroll 1
        for (int c0 = 0; c0 < C; c0 += 4) {
            float v[4];
#pragma unroll
            for (int j = 0; j < 4; ++j) {
                size_t cs = (size_t)(c0 + j) * HXW;
                v[j] = w00 * p00[cs] + w01 * p01[cs] + w10 * p10[cs] + w11 * p11[cs];
            }
            const float* wr = wk + c0 * O;
#pragma unroll
            for (int j = 0; j < 4; ++j)
#pragma unroll
                for (int o = 0; o < O; ++o) acc[o] = fmaf(wr[j * O + o], v[j], acc[o]);
        }
    }
#pragma unroll
    for (int o = 0; o < O; ++o) out[((size_t)(b * O + o)) * HXW + hw] = acc[o];
}

// ---------------- prep: xbt NHWC bf16 + lane-packed bf16 weights ----------------
// blocks [0,512): x NCHW fp32 -> xbt [B][H][W][64] bf16 (128 B/pixel = 1 line)
// blocks [512,512+144): weight[O][C][K] -> wtb2[k][s][lane][8] bf16 where the
//   B-fragment load for (k, ks, nf) is lane-linear: s = ks*4+nf,
//   element = weight[o = nf*16+(lane&15)][c = ks*32+(lane>>4)*8+e][k].
constexpr int XT_BLOCKS = B * HXW / 128;   // 512
__global__ __launch_bounds__(256) void prep_kernel(
        const float* __restrict__ x, const float* __restrict__ weight,
        short* __restrict__ xbt, short* __restrict__ wtb2) {
    int bid = blockIdx.x;
    if (bid < XT_BLOCKS) {
        __shared__ float lds[128 * 65];
        int t = threadIdx.x;
        int P = bid * 128;
        int b = P >> 14;
        int hw0 = P & (HXW - 1);
        int px = t & 127;
        int hf = t >> 7;
        const float* src = x + (size_t)b * C * HXW + hw0 + px;
#pragma unroll
        for (int cc = 0; cc < 32; ++cc) {
            int ch = hf * 32 + cc;
            lds[px * 65 + ch] = src[(size_t)ch * HXW];
        }
        __syncthreads();
        short* dst = xbt + ((size_t)b * HXW + hw0 + px) * 64 + hf * 32;
        const float* row = lds + px * 65 + hf * 32;
#pragma unroll
        for (int j = 0; j < 4; ++j) {
            short8 pk;
#pragma unroll
            for (int e = 0; e < 8; ++e) pk[e] = f2bf(row[j * 8 + e]);
            *(short8*)(dst + j * 8) = pk;
        }
    } else {
        int idx = (bid - XT_BLOCKS) * 256 + threadIdx.x;
        if (idx < K * O * C) {
            int e = idx & 7;
            int lane = (idx >> 3) & 63;
            int s = (idx >> 9) & 7;
            int k = idx >> 12;
            int ml = lane & 15, kg = lane >> 4;
            int nf = s & 3, ks = s >> 2;
            int o = nf * 16 + ml;
            int c = ks * 32 + kg * 8 + e;
            wtb2[idx] = f2bf(weight[(o * C + c) * K + k]);
        }
    }
}

// ---------------- main: line-packed gather + wave-private LDS + MFMA ----------------
// 512 blocks x 256 threads; block = one 128-px image row; wave = 32 px x 64 out.
// Gather: lane (p8=lane>>3, ch8=lane&7); one instr = 8 full pixel records = 8 lines.
// A-tile: wave-private LDS [32 px][8 slots x 8ch] with slot ^= px&7 swizzle.
// No barriers anywhere in the k-loop.
__global__ __launch_bounds__(256, 2) void mdcn_bf16(
        const short* __restrict__ xbt,     // [B][H][W][64] bf16
        const float* __restrict__ offset,  // [B][2K][H][W]
        const float* __restrict__ mask,    // [B][K][H][W]
        const short* __restrict__ wtb2,    // [K][8][64][8] bf16 lane-packed
        const float* __restrict__ bias,    // [O]
        float* __restrict__ out) {         // [B][O][H][W]
    __shared__ short Alds[4][32 * 64];     // 4 KB per wave, wave-private

    int bid = blockIdx.x;
    int slab = bid & 7;                    // -> XCD; (batch, half-image)
    int within = bid >> 3;                 // 0..63
    int tid = threadIdx.x;
    int lane = tid & 63;
    int wid = tid >> 6;
    int ml = lane & 15, kg = lane >> 4;
    int p8 = lane >> 3, ch8 = lane & 7;
    int b = slab >> 1;
    int hwrow = (slab & 1) * 8192 + within * 128;  // row-aligned
    int h = hwrow >> 7;
    int wvpx = wid * 32;                   // wave's first pixel within the row
    short* Aw = &Alds[wid][0];

    f32x4 acc[2][4];
#pragma unroll
    for (int nf = 0; nf < 4; ++nf) {
        float bv = bias[nf * 16 + ml];
        acc[0][nf] = (f32x4){bv, bv, bv, bv};
        acc[1][nf] = (f32x4){bv, bv, bv, bv};
    }

    const short* xb = xbt + (size_t)b * HXW * 64;
    const float* offb = offset + (size_t)b * 2 * K * HXW;
    const float* mskb = mask + (size_t)b * K * HXW;

#pragma unroll 1
    for (int k = 0; k < K; ++k) {
        int ky = k / 3 - 1, kx = k % 3 - 1;

        // ---- gather + combine + A-tile write: 4 groups x 8 px ----
#pragma unroll
        for (int g = 0; g < 4; ++g) {
            int pl = g * 8 + p8;           // wave-local pixel 0..31
            int hw = hwrow + wvpx + pl;
            int w = wvpx + pl;

            float offy = offb[(size_t)(2 * k) * HXW + hw];
            float offx = offb[(size_t)(2 * k + 1) * HXW + hw];
            float m    = mskb[(size_t)k * HXW + hw];

            float sy = (float)(h + ky) + offy;
            float sx = (float)(w + kx) + offx;
            float y0f = floorf(sy), x0f = floorf(sx);
            float wy = sy - y0f, wx = sx - x0f;
            int y0 = (int)y0f, x0 = (int)x0f;
            int y1 = y0 + 1, x1 = x0 + 1;
            bool vy0 = (y0 >= 0) & (y0 < H), vy1 = (y1 >= 0) & (y1 < H);
            bool vx0 = (x0 >= 0) & (x0 < W), vx1 = (x1 >= 0) & (x1 < W);
            float w00 = (vy0 & vx0) ? (1.0f - wy) * (1.0f - wx) * m : 0.0f;
            float w01 = (vy0 & vx1) ? (1.0f - wy) * wx * m : 0.0f;
            float w10 = (vy1 & vx0) ? wy * (1.0f - wx) * m : 0.0f;
            float w11 = (vy1 & vx1) ? wy * wx * m : 0.0f;
            int y0c = min(max(y0, 0), H - 1), y1c = min(max(y1, 0), H - 1);
            int x0c = min(max(x0, 0), W - 1), x1c = min(max(x1, 0), W - 1);

            int r00 = y0c * W + x0c, r01 = y0c * W + x1c;
            int r10 = y1c * W + x0c, r11 = y1c * W + x1c;

            // 4 corner loads: 8 lanes cover one full 128-B record -> 8 lines/instr
            short8 a00 = *(const short8*)(xb + r00 * 64 + ch8 * 8);
            short8 a01 = *(const short8*)(xb + r01 * 64 + ch8 * 8);
            short8 a10 = *(const short8*)(xb + r10 * 64 + ch8 * 8);
            short8 a11 = *(const short8*)(xb + r11 * 64 + ch8 * 8);

            short8 pk;
#pragma unroll
            for (int e = 0; e < 8; ++e)
                pk[e] = f2bf(w00 * bf2f(a00[e]) + w01 * bf2f(a01[e]) +
                             w10 * bf2f(a10[e]) + w11 * bf2f(a11[e]));
            *(short8*)(Aw + pl * 64 + ((ch8 ^ (pl & 7)) * 8)) = pk;
        }

        // ---- MFMA: read A-frags from wave-private LDS, B-frags lane-linear ----
#pragma unroll
        for (int ks = 0; ks < 2; ++ks) {
            short8 bfr[4];
#pragma unroll
            for (int nf = 0; nf < 4; ++nf)
                bfr[nf] = *(const short8*)(wtb2 + ((size_t)((k * 8 + ks * 4 + nf) * 64 + lane)) * 8);
            short8 af[2];
#pragma unroll
            for (int mf = 0; mf < 2; ++mf) {
                int row = mf * 16 + ml;
                af[mf] = *(const short8*)(Aw + row * 64 + (((ks * 4 + kg) ^ (row & 7)) * 8));
            }
#pragma unroll
            for (int mf = 0; mf < 2; ++mf)
#pragma unroll
                for (int nf = 0; nf < 4; ++nf)
                    acc[mf][nf] = __builtin_amdgcn_mfma_f32_16x16x32_bf16(
                        af[mf], bfr[nf], acc[mf][nf], 0, 0, 0);
        }
    }

    // ---- store: D row(px) = kg*4 + reg, col(o) = nf*16 + ml ----
    int hwb = hwrow + wvpx;
#pragma unroll
    for (int mf = 0; mf < 2; ++mf)
#pragma unroll
        for (int nf = 0; nf < 4; ++nf) {
            size_t ob = ((size_t)(b * O + nf * 16 + ml)) * HXW + hwb + mf * 16 + kg * 4;
            *(float4*)(out + ob) = __builtin_bit_cast(float4, acc[mf][nf]);
        }
}

extern "C" void kernel_launch(void* const* d_in, const int* in_sizes, int n_in,
                              void* d_out, int out_size, void* d_ws, size_t ws_size,
                              hipStream_t stream) {
    const float* x      = (const float*)d_in[0];
    const float* offset = (const float*)d_in[1];
    const float* mask   = (const float*)d_in[2];
    const float* weight = (const float*)d_in[3];
    const float* bias   = (const float*)d_in[4];
    float* out = (float*)d_out;

    short* wtb2 = (short*)d_ws;                                   // 73728 B
    short* xbt  = (short*)((char*)d_ws + 73728);                  // 8.39 MB
    size_t need = 73728 + (size_t)B * HXW * 64 * sizeof(short);

    if (ws_size >= need) {
        int wtb_blocks = (K * O * C + 255) / 256;                 // 144
        prep_kernel<<<XT_BLOCKS + wtb_blocks, 256, 0, stream>>>(x, weight, xbt, wtb2);
        mdcn_bf16<<<512, 256, 0, stream>>>(xbt, offset, mask, wtb2, bias, out);
    } else {
        float* wt = (float*)d_ws;                                 // 147456 B (fallback)
        wt_kernel<<<(K * C * O + 255) / 256, 256, 0, stream>>>(weight, wt);
        mdcn_nchw<<<(B * HXW) / 256, 256, 0, stream>>>(x, offset, mask, wt, bias, out);
    }
}

// Round 7
// 41.864 us; speedup vs baseline: 2.8873x; 1.0889x over previous
//
#include <hip/hip_runtime.h>
#include <hip/hip_bf16.h>
#include <math.h>

constexpr int B = 4, C = 64, H = 128, W = 128, K = 9, O = 64;
constexpr int HXW = H * W;

typedef short short8 __attribute__((ext_vector_type(8)));
typedef float f32x4 __attribute__((ext_vector_type(4)));

static __device__ __forceinline__ short f2bf(float v) {
    __hip_bfloat16 h = __float2bfloat16(v);
    return (short)__builtin_bit_cast(unsigned short, h);
}
static __device__ __forceinline__ float bf2f(short s) {
    unsigned int u = ((unsigned int)(unsigned short)s) << 16;
    return __builtin_bit_cast(float, u);
}

// ---------------- fallback path (fp32, proven round 1) ----------------
__global__ void wt_kernel(const float* __restrict__ weight, float* __restrict__ wt) {
    int idx = blockIdx.x * 256 + threadIdx.x;
    if (idx >= K * C * O) return;
    int o = idx & 63;
    int c = (idx >> 6) & 63;
    int k = idx >> 12;
    wt[idx] = weight[(o * C + c) * K + k];
}

__global__ __launch_bounds__(256) void mdcn_nchw(
        const float* __restrict__ x, const float* __restrict__ offset,
        const float* __restrict__ mask, const float* __restrict__ wt,
        const float* __restrict__ bias, float* __restrict__ out) {
    int pid = blockIdx.x * 256 + threadIdx.x;
    int b = pid >> 14;
    int hw = pid & (HXW - 1);
    int h = hw >> 7;
    int w = hw & 127;
    float acc[O];
#pragma unroll
    for (int o = 0; o < O; ++o) acc[o] = bias[o];
#pragma unroll 1
    for (int k = 0; k < K; ++k) {
        float offy = offset[((size_t)(b * 2 * K + 2 * k)) * HXW + hw];
        float offx = offset[((size_t)(b * 2 * K + 2 * k + 1)) * HXW + hw];
        float m    = mask[((size_t)(b * K + k)) * HXW + hw];
        float sy = (float)(h - 1 + k / 3) + offy;
        float sx = (float)(w - 1 + k % 3) + offx;
        float y0f = floorf(sy), x0f = floorf(sx);
        float wy = sy - y0f, wx = sx - x0f;
        int y0 = (int)y0f, x0 = (int)x0f;
        int y1 = y0 + 1, x1 = x0 + 1;
        bool vy0 = (y0 >= 0) & (y0 < H), vy1 = (y1 >= 0) & (y1 < H);
        bool vx0 = (x0 >= 0) & (x0 < W), vx1 = (x1 >= 0) & (x1 < W);
        float w00 = (vy0 & vx0) ? (1.0f - wy) * (1.0f - wx) * m : 0.0f;
        float w01 = (vy0 & vx1) ? (1.0f - wy) * wx * m : 0.0f;
        float w10 = (vy1 & vx0) ? wy * (1.0f - wx) * m : 0.0f;
        float w11 = (vy1 & vx1) ? wy * wx * m : 0.0f;
        int y0c = min(max(y0, 0), H - 1), y1c = min(max(y1, 0), H - 1);
        int x0c = min(max(x0, 0), W - 1), x1c = min(max(x1, 0), W - 1);
        const float* p00 = x + (size_t)b * C * HXW + y0c * W + x0c;
        const float* p01 = x + (size_t)b * C * HXW + y0c * W + x1c;
        const float* p10 = x + (size_t)b * C * HXW + y1c * W + x0c;
        const float* p11 = x + (size_t)b * C * HXW + y1c * W + x1c;
        const float* wk = wt + k * C * O;
#pragma unroll 1
        for (int c0 = 0; c0 < C; c0 += 4) {
            float v[4];
#pragma unroll
            for (int j = 0; j < 4; ++j) {
                size_t cs = (size_t)(c0 + j) * HXW;
                v[j] = w00 * p00[cs] + w01 * p01[cs] + w10 * p10[cs] + w11 * p11[cs];
            }
            const float* wr = wk + c0 * O;
#pragma unroll
            for (int j = 0; j < 4; ++j)
#pragma unroll
                for (int o = 0; o < O; ++o) acc[o] = fmaf(wr[j * O + o], v[j], acc[o]);
        }
    }
#pragma unroll
    for (int o = 0; o < O; ++o) out[((size_t)(b * O + o)) * HXW + hw] = acc[o];
}

// ---------------- prep: xbt NHWC bf16 + lane-packed bf16 weights ----------------
constexpr int XT_BLOCKS = B * HXW / 128;   // 512
__global__ __launch_bounds__(256) void prep_kernel(
        const float* __restrict__ x, const float* __restrict__ weight,
        short* __restrict__ xbt, short* __restrict__ wtb2) {
    int bid = blockIdx.x;
    if (bid < XT_BLOCKS) {
        __shared__ float lds[128 * 65];
        int t = threadIdx.x;
        int P = bid * 128;
        int b = P >> 14;
        int hw0 = P & (HXW - 1);
        int px = t & 127;
        int hf = t >> 7;
        const float* src = x + (size_t)b * C * HXW + hw0 + px;
#pragma unroll
        for (int cc = 0; cc < 32; ++cc) {
            int ch = hf * 32 + cc;
            lds[px * 65 + ch] = src[(size_t)ch * HXW];
        }
        __syncthreads();
        short* dst = xbt + ((size_t)b * HXW + hw0 + px) * 64 + hf * 32;
        const float* row = lds + px * 65 + hf * 32;
#pragma unroll
        for (int j = 0; j < 4; ++j) {
            short8 pk;
#pragma unroll
            for (int e = 0; e < 8; ++e) pk[e] = f2bf(row[j * 8 + e]);
            *(short8*)(dst + j * 8) = pk;
        }
    } else {
        int idx = (bid - XT_BLOCKS) * 256 + threadIdx.x;
        if (idx < K * O * C) {
            int e = idx & 7;
            int lane = (idx >> 3) & 63;
            int s = (idx >> 9) & 7;
            int k = idx >> 12;
            int ml = lane & 15, kg = lane >> 4;
            int nf = s & 3, ks = s >> 2;
            int o = nf * 16 + ml;
            int c = ks * 32 + kg * 8 + e;
            wtb2[idx] = f2bf(weight[(o * C + c) * K + k]);
        }
    }
}

// ---------------- main: phase-batched pipelined gather + wave-private LDS + MFMA ----
// 512 blocks x 256 threads; block = one 128-px image row; wave = 32 px x 64 out.
// Tap body phases: (2) weights+addrs [VALU] -> (3) issue ALL 16 gathers ->
// (3.5) prefetch next tap's offsets -> sched_barrier -> (4) combine -> (5) MFMA.
__global__ __launch_bounds__(256, 2) void mdcn_bf16(
        const short* __restrict__ xbt,     // [B][H][W][64] bf16
        const float* __restrict__ offset,  // [B][2K][H][W]
        const float* __restrict__ mask,    // [B][K][H][W]
        const short* __restrict__ wtb2,    // [K][8][64][8] bf16 lane-packed
        const float* __restrict__ bias,    // [O]
        float* __restrict__ out) {         // [B][O][H][W]
    __shared__ short Alds[4][32 * 64];     // 4 KB per wave, wave-private

    int bid = blockIdx.x;
    int slab = bid & 7;                    // -> XCD; (batch, half-image)
    int within = bid >> 3;                 // 0..63
    int tid = threadIdx.x;
    int lane = tid & 63;
    int wid = tid >> 6;
    int ml = lane & 15, kg = lane >> 4;
    int p8 = lane >> 3, ch8 = lane & 7;
    int b = slab >> 1;
    int hwrow = (slab & 1) * 8192 + within * 128;  // row-aligned
    int h = hwrow >> 7;
    int wvpx = wid * 32;
    short* Aw = &Alds[wid][0];

    f32x4 acc[2][4];
#pragma unroll
    for (int nf = 0; nf < 4; ++nf) {
        float bv = bias[nf * 16 + ml];
        acc[0][nf] = (f32x4){bv, bv, bv, bv};
        acc[1][nf] = (f32x4){bv, bv, bv, bv};
    }

    const short* xb = xbt + (size_t)b * HXW * 64;
    const float* offb = offset + (size_t)b * 2 * K * HXW;
    const float* mskb = mask + (size_t)b * K * HXW;

    // prologue: offsets for tap 0
    float oy[4], ox[4], mm[4];
#pragma unroll
    for (int g = 0; g < 4; ++g) {
        int hw = hwrow + wvpx + g * 8 + p8;
        oy[g] = offb[hw];
        ox[g] = offb[(size_t)HXW + hw];
        mm[g] = mskb[hw];
    }

#pragma unroll 1
    for (int k = 0; k < K; ++k) {
        int ky = k / 3 - 1, kx = k % 3 - 1;

        // ---- phase 2: weights + record indices (pure VALU) ----
        float w00[4], w01[4], w10[4], w11[4];
        int r00[4], r01[4], r10[4], r11[4];
#pragma unroll
        for (int g = 0; g < 4; ++g) {
            int pl = g * 8 + p8;
            int w = wvpx + pl;
            float sy = (float)(h + ky) + oy[g];
            float sx = (float)(w + kx) + ox[g];
            float y0f = floorf(sy), x0f = floorf(sx);
            float wy = sy - y0f, wx = sx - x0f;
            int y0 = (int)y0f, x0 = (int)x0f;
            int y1 = y0 + 1, x1 = x0 + 1;
            bool vy0 = (y0 >= 0) & (y0 < H), vy1 = (y1 >= 0) & (y1 < H);
            bool vx0 = (x0 >= 0) & (x0 < W), vx1 = (x1 >= 0) & (x1 < W);
            float m = mm[g];
            w00[g] = (vy0 & vx0) ? (1.0f - wy) * (1.0f - wx) * m : 0.0f;
            w01[g] = (vy0 & vx1) ? (1.0f - wy) * wx * m : 0.0f;
            w10[g] = (vy1 & vx0) ? wy * (1.0f - wx) * m : 0.0f;
            w11[g] = (vy1 & vx1) ? wy * wx * m : 0.0f;
            int y0c = min(max(y0, 0), H - 1), y1c = min(max(y1, 0), H - 1);
            int x0c = min(max(x0, 0), W - 1), x1c = min(max(x1, 0), W - 1);
            r00[g] = y0c * W + x0c;
            r01[g] = y0c * W + x1c;
            r10[g] = y1c * W + x0c;
            r11[g] = y1c * W + x1c;
        }

        // ---- phase 3: issue ALL 16 gathers back-to-back ----
        short8 c00[4], c01[4], c10[4], c11[4];
#pragma unroll
        for (int g = 0; g < 4; ++g) {
            c00[g] = *(const short8*)(xb + r00[g] * 64 + ch8 * 8);
            c01[g] = *(const short8*)(xb + r01[g] * 64 + ch8 * 8);
            c10[g] = *(const short8*)(xb + r10[g] * 64 + ch8 * 8);
            c11[g] = *(const short8*)(xb + r11[g] * 64 + ch8 * 8);
        }

        // ---- phase 3.5: prefetch next tap's offsets (hidden under gathers) ----
        float oy2[4], ox2[4], mm2[4];
        if (k + 1 < K) {
#pragma unroll
            for (int g = 0; g < 4; ++g) {
                int hw = hwrow + wvpx + g * 8 + p8;
                oy2[g] = offb[(size_t)(2 * k + 2) * HXW + hw];
                ox2[g] = offb[(size_t)(2 * k + 3) * HXW + hw];
                mm2[g] = mskb[(size_t)(k + 1) * HXW + hw];
            }
        }
        __builtin_amdgcn_sched_barrier(0);   // pin: loads above, consumers below

        // ---- phase 4: combine -> wave-private LDS A-tile ----
#pragma unroll
        for (int g = 0; g < 4; ++g) {
            int pl = g * 8 + p8;
            short8 pk;
#pragma unroll
            for (int e = 0; e < 8; ++e)
                pk[e] = f2bf(w00[g] * bf2f(c00[g][e]) + w01[g] * bf2f(c01[g][e]) +
                             w10[g] * bf2f(c10[g][e]) + w11[g] * bf2f(c11[g][e]));
            *(short8*)(Aw + pl * 64 + ((ch8 ^ (pl & 7)) * 8)) = pk;
        }

        // ---- phase 5: MFMA ----
#pragma unroll
        for (int ks = 0; ks < 2; ++ks) {
            short8 bfr[4];
#pragma unroll
            for (int nf = 0; nf < 4; ++nf)
                bfr[nf] = *(const short8*)(wtb2 + ((size_t)((k * 8 + ks * 4 + nf) * 64 + lane)) * 8);
            short8 af[2];
#pragma unroll
            for (int mf = 0; mf < 2; ++mf) {
                int row = mf * 16 + ml;
                af[mf] = *(const short8*)(Aw + row * 64 + (((ks * 4 + kg) ^ (row & 7)) * 8));
            }
#pragma unroll
            for (int mf = 0; mf < 2; ++mf)
#pragma unroll
                for (int nf = 0; nf < 4; ++nf)
                    acc[mf][nf] = __builtin_amdgcn_mfma_f32_16x16x32_bf16(
                        af[mf], bfr[nf], acc[mf][nf], 0, 0, 0);
        }

        // rotate prefetched offsets into place
        if (k + 1 < K) {
#pragma unroll
            for (int g = 0; g < 4; ++g) { oy[g] = oy2[g]; ox[g] = ox2[g]; mm[g] = mm2[g]; }
        }
    }

    // ---- store: D row(px) = kg*4 + reg, col(o) = nf*16 + ml ----
    int hwb = hwrow + wvpx;
#pragma unroll
    for (int mf = 0; mf < 2; ++mf)
#pragma unroll
        for (int nf = 0; nf < 4; ++nf) {
            size_t ob = ((size_t)(b * O + nf * 16 + ml)) * HXW + hwb + mf * 16 + kg * 4;
            *(float4*)(out + ob) = __builtin_bit_cast(float4, acc[mf][nf]);
        }
}

extern "C" void kernel_launch(void* const* d_in, const int* in_sizes, int n_in,
                              void* d_out, int out_size, void* d_ws, size_t ws_size,
                              hipStream_t stream) {
    const float* x      = (const float*)d_in[0];
    const float* offset = (const float*)d_in[1];
    const float* mask   = (const float*)d_in[2];
    const float* weight = (const float*)d_in[3];
    const float* bias   = (const float*)d_in[4];
    float* out = (float*)d_out;

    short* wtb2 = (short*)d_ws;                                   // 73728 B
    short* xbt  = (short*)((char*)d_ws + 73728);                  // 8.39 MB
    size_t need = 73728 + (size_t)B * HXW * 64 * sizeof(short);

    if (ws_size >= need) {
        int wtb_blocks = (K * O * C + 255) / 256;                 // 144
        prep_kernel<<<XT_BLOCKS + wtb_blocks, 256, 0, stream>>>(x, weight, xbt, wtb2);
        mdcn_bf16<<<512, 256, 0, stream>>>(xbt, offset, mask, wtb2, bias, out);
    } else {
        float* wt = (float*)d_ws;                                 // 147456 B (fallback)
        wt_kernel<<<(K * C * O + 255) / 256, 256, 0, stream>>>(weight, wt);
        mdcn_nchw<<<(B * HXW) / 256, 256, 0, stream>>>(x, offset, mask, wt, bias, out);
    }
}

// Round 8
// 39.417 us; speedup vs baseline: 3.0665x; 1.0621x over previous
//
#include <hip/hip_runtime.h>
#include <hip/hip_bf16.h>
#include <math.h>

constexpr int B = 4, C = 64, H = 128, W = 128, K = 9, O = 64;
constexpr int HXW = H * W;

typedef _Float16 half8 __attribute__((ext_vector_type(8)));
typedef float f32x4 __attribute__((ext_vector_type(4)));

// ---------------- fallback path (fp32, proven round 1) ----------------
__global__ void wt_kernel(const float* __restrict__ weight, float* __restrict__ wt) {
    int idx = blockIdx.x * 256 + threadIdx.x;
    if (idx >= K * C * O) return;
    int o = idx & 63;
    int c = (idx >> 6) & 63;
    int k = idx >> 12;
    wt[idx] = weight[(o * C + c) * K + k];
}

__global__ __launch_bounds__(256) void mdcn_nchw(
        const float* __restrict__ x, const float* __restrict__ offset,
        const float* __restrict__ mask, const float* __restrict__ wt,
        const float* __restrict__ bias, float* __restrict__ out) {
    int pid = blockIdx.x * 256 + threadIdx.x;
    int b = pid >> 14;
    int hw = pid & (HXW - 1);
    int h = hw >> 7;
    int w = hw & 127;
    float acc[O];
#pragma unroll
    for (int o = 0; o < O; ++o) acc[o] = bias[o];
#pragma unroll 1
    for (int k = 0; k < K; ++k) {
        float offy = offset[((size_t)(b * 2 * K + 2 * k)) * HXW + hw];
        float offx = offset[((size_t)(b * 2 * K + 2 * k + 1)) * HXW + hw];
        float m    = mask[((size_t)(b * K + k)) * HXW + hw];
        float sy = (float)(h - 1 + k / 3) + offy;
        float sx = (float)(w - 1 + k % 3) + offx;
        float y0f = floorf(sy), x0f = floorf(sx);
        float wy = sy - y0f, wx = sx - x0f;
        int y0 = (int)y0f, x0 = (int)x0f;
        int y1 = y0 + 1, x1 = x0 + 1;
        bool vy0 = (y0 >= 0) & (y0 < H), vy1 = (y1 >= 0) & (y1 < H);
        bool vx0 = (x0 >= 0) & (x0 < W), vx1 = (x1 >= 0) & (x1 < W);
        float w00 = (vy0 & vx0) ? (1.0f - wy) * (1.0f - wx) * m : 0.0f;
        float w01 = (vy0 & vx1) ? (1.0f - wy) * wx * m : 0.0f;
        float w10 = (vy1 & vx0) ? wy * (1.0f - wx) * m : 0.0f;
        float w11 = (vy1 & vx1) ? wy * wx * m : 0.0f;
        int y0c = min(max(y0, 0), H - 1), y1c = min(max(y1, 0), H - 1);
        int x0c = min(max(x0, 0), W - 1), x1c = min(max(x1, 0), W - 1);
        const float* p00 = x + (size_t)b * C * HXW + y0c * W + x0c;
        const float* p01 = x + (size_t)b * C * HXW + y0c * W + x1c;
        const float* p10 = x + (size_t)b * C * HXW + y1c * W + x0c;
        const float* p11 = x + (size_t)b * C * HXW + y1c * W + x1c;
        const float* wk = wt + k * C * O;
#pragma unroll 1
        for (int c0 = 0; c0 < C; c0 += 4) {
            float v[4];
#pragma unroll
            for (int j = 0; j < 4; ++j) {
                size_t cs = (size_t)(c0 + j) * HXW;
                v[j] = w00 * p00[cs] + w01 * p01[cs] + w10 * p10[cs] + w11 * p11[cs];
            }
            const float* wr = wk + c0 * O;
#pragma unroll
            for (int j = 0; j < 4; ++j)
#pragma unroll
                for (int o = 0; o < O; ++o) acc[o] = fmaf(wr[j * O + o], v[j], acc[o]);
        }
    }
#pragma unroll
    for (int o = 0; o < O; ++o) out[((size_t)(b * O + o)) * HXW + hw] = acc[o];
}

// ---------------- prep: xht NHWC fp16 + lane-packed fp16 weights ----------------
// blocks [0,512): x NCHW fp32 -> xht [B][H][W][64] fp16 (128 B/pixel = 1 line)
// blocks [512,512+144): weight[O][C][K] -> wth[k][s][lane][8] fp16, lane-linear
//   B-fragment layout: s = ks*4+nf, elem = weight[o=nf*16+(lane&15)][c=ks*32+(lane>>4)*8+e][k]
constexpr int XT_BLOCKS = B * HXW / 128;   // 512
__global__ __launch_bounds__(256) void prep_kernel(
        const float* __restrict__ x, const float* __restrict__ weight,
        _Float16* __restrict__ xht, _Float16* __restrict__ wth) {
    int bid = blockIdx.x;
    if (bid < XT_BLOCKS) {
        __shared__ float lds[128 * 65];
        int t = threadIdx.x;
        int P = bid * 128;
        int b = P >> 14;
        int hw0 = P & (HXW - 1);
        int px = t & 127;
        int hf = t >> 7;
        const float* src = x + (size_t)b * C * HXW + hw0 + px;
#pragma unroll
        for (int cc = 0; cc < 32; ++cc) {
            int ch = hf * 32 + cc;
            lds[px * 65 + ch] = src[(size_t)ch * HXW];
        }
        __syncthreads();
        _Float16* dst = xht + ((size_t)b * HXW + hw0 + px) * 64 + hf * 32;
        const float* row = lds + px * 65 + hf * 32;
#pragma unroll
        for (int j = 0; j < 4; ++j) {
            half8 pk;
#pragma unroll
            for (int e = 0; e < 8; ++e) pk[e] = (_Float16)row[j * 8 + e];
            *(half8*)(dst + j * 8) = pk;
        }
    } else {
        int idx = (bid - XT_BLOCKS) * 256 + threadIdx.x;
        if (idx < K * O * C) {
            int e = idx & 7;
            int lane = (idx >> 3) & 63;
            int s = (idx >> 9) & 7;
            int k = idx >> 12;
            int ml = lane & 15, kg = lane >> 4;
            int nf = s & 3, ks = s >> 2;
            int o = nf * 16 + ml;
            int c = ks * 32 + kg * 8 + e;
            wth[idx] = (_Float16)weight[(o * C + c) * K + k];
        }
    }
}

// ---------------- main: 16-px waves, fp16 packed combine, f16 MFMA ----------------
// 1024 blocks x 256 threads; block = 64 px (half image row); wave = 16 px x 64 out.
// Gather: lane (p8=lane>>3, ch8=lane&7); one instr = 8 full 128-B records = 8 lines.
// A-tile: wave-private LDS [16 px][8 slots x 8ch] fp16 with slot ^= px&7 swizzle.
// No barriers in the k-loop. slab = bid & 7 -> XCD-local L2 working set.
__global__ __launch_bounds__(256, 4) void mdcn_f16(
        const _Float16* __restrict__ xht,  // [B][H][W][64] fp16
        const float* __restrict__ offset,  // [B][2K][H][W]
        const float* __restrict__ mask,    // [B][K][H][W]
        const _Float16* __restrict__ wth,  // [K][8][64][8] fp16 lane-packed
        const float* __restrict__ bias,    // [O]
        float* __restrict__ out) {         // [B][O][H][W]
    __shared__ _Float16 Alds[4][16 * 64];  // 2 KB per wave, wave-private

    int bid = blockIdx.x;
    int slab = bid & 7;                    // (batch, half-image) -> XCD
    int within = bid >> 3;                 // 0..127
    int tid = threadIdx.x;
    int lane = tid & 63;
    int wid = tid >> 6;
    int ml = lane & 15, kg = lane >> 4;
    int p8 = lane >> 3, ch8 = lane & 7;
    int b = slab >> 1;
    int hwbase = (slab & 1) * 8192 + within * 64;  // 64-px chunk, one row
    int h = hwbase >> 7;
    int wvpx = wid * 16;                   // wave's first pixel within the chunk
    int wbase = (hwbase & 127) + wvpx;     // image x of wave's first pixel
    _Float16* Aw = &Alds[wid][0];

    f32x4 acc[4];
#pragma unroll
    for (int nf = 0; nf < 4; ++nf) {
        float bv = bias[nf * 16 + ml];
        acc[nf] = (f32x4){bv, bv, bv, bv};
    }

    const _Float16* xb = xht + (size_t)b * HXW * 64;
    const float* offb = offset + (size_t)b * 2 * K * HXW;
    const float* mskb = mask + (size_t)b * K * HXW;

    // prologue: offsets for tap 0
    float oy[2], ox[2], mm[2];
#pragma unroll
    for (int g = 0; g < 2; ++g) {
        int hw = hwbase + wvpx + g * 8 + p8;
        oy[g] = offb[hw];
        ox[g] = offb[(size_t)HXW + hw];
        mm[g] = mskb[hw];
    }

#pragma unroll 1
    for (int k = 0; k < K; ++k) {
        int ky = k / 3 - 1, kx = k % 3 - 1;

        // ---- phase 2: corner weights + record indices (pure VALU) ----
        float w00[2], w01[2], w10[2], w11[2];
        int r00[2], r01[2], r10[2], r11[2];
#pragma unroll
        for (int g = 0; g < 2; ++g) {
            int pl = g * 8 + p8;
            int w = wbase + pl;
            float sy = (float)(h + ky) + oy[g];
            float sx = (float)(w + kx) + ox[g];
            float y0f = floorf(sy), x0f = floorf(sx);
            float wy = sy - y0f, wx = sx - x0f;
            int y0 = (int)y0f, x0 = (int)x0f;
            int y1 = y0 + 1, x1 = x0 + 1;
            bool vy0 = (y0 >= 0) & (y0 < H), vy1 = (y1 >= 0) & (y1 < H);
            bool vx0 = (x0 >= 0) & (x0 < W), vx1 = (x1 >= 0) & (x1 < W);
            float m = mm[g];
            w00[g] = (vy0 & vx0) ? (1.0f - wy) * (1.0f - wx) * m : 0.0f;
            w01[g] = (vy0 & vx1) ? (1.0f - wy) * wx * m : 0.0f;
            w10[g] = (vy1 & vx0) ? wy * (1.0f - wx) * m : 0.0f;
            w11[g] = (vy1 & vx1) ? wy * wx * m : 0.0f;
            int y0c = min(max(y0, 0), H - 1), y1c = min(max(y1, 0), H - 1);
            int x0c = min(max(x0, 0), W - 1), x1c = min(max(x1, 0), W - 1);
            r00[g] = y0c * W + x0c;
            r01[g] = y0c * W + x1c;
            r10[g] = y1c * W + x0c;
            r11[g] = y1c * W + x1c;
        }

        // ---- phase 3: issue ALL 8 gathers back-to-back ----
        half8 c00[2], c01[2], c10[2], c11[2];
#pragma unroll
        for (int g = 0; g < 2; ++g) {
            c00[g] = *(const half8*)(xb + r00[g] * 64 + ch8 * 8);
            c01[g] = *(const half8*)(xb + r01[g] * 64 + ch8 * 8);
            c10[g] = *(const half8*)(xb + r10[g] * 64 + ch8 * 8);
            c11[g] = *(const half8*)(xb + r11[g] * 64 + ch8 * 8);
        }

        // ---- phase 3.5: prefetch next tap's offsets (hidden under gathers) ----
        float oy2[2], ox2[2], mm2[2];
        if (k + 1 < K) {
#pragma unroll
            for (int g = 0; g < 2; ++g) {
                int hw = hwbase + wvpx + g * 8 + p8;
                oy2[g] = offb[(size_t)(2 * k + 2) * HXW + hw];
                ox2[g] = offb[(size_t)(2 * k + 3) * HXW + hw];
                mm2[g] = mskb[(size_t)(k + 1) * HXW + hw];
            }
        }
        __builtin_amdgcn_sched_barrier(0);   // pin: loads above, consumers below

        // ---- phase 4: packed-fp16 combine -> wave-private LDS A-tile ----
#pragma unroll
        for (int g = 0; g < 2; ++g) {
            int pl = g * 8 + p8;
            _Float16 h00 = (_Float16)w00[g], h01 = (_Float16)w01[g];
            _Float16 h10 = (_Float16)w10[g], h11 = (_Float16)w11[g];
            half8 pk = c00[g] * h00 + c01[g] * h01 + c10[g] * h10 + c11[g] * h11;
            *(half8*)(Aw + pl * 64 + ((ch8 ^ (pl & 7)) * 8)) = pk;
        }

        // ---- phase 5: MFMA ----
#pragma unroll
        for (int ks = 0; ks < 2; ++ks) {
            half8 bfr[4];
#pragma unroll
            for (int nf = 0; nf < 4; ++nf)
                bfr[nf] = *(const half8*)(wth + ((size_t)((k * 8 + ks * 4 + nf) * 64 + lane)) * 8);
            half8 af = *(const half8*)(Aw + ml * 64 + (((ks * 4 + kg) ^ (ml & 7)) * 8));
#pragma unroll
            for (int nf = 0; nf < 4; ++nf)
                acc[nf] = __builtin_amdgcn_mfma_f32_16x16x32_f16(af, bfr[nf], acc[nf], 0, 0, 0);
        }

        // rotate prefetched offsets into place
        if (k + 1 < K) {
#pragma unroll
            for (int g = 0; g < 2; ++g) { oy[g] = oy2[g]; ox[g] = ox2[g]; mm[g] = mm2[g]; }
        }
    }

    // ---- store: D row(px) = kg*4 + reg, col(o) = nf*16 + ml ----
    int hwb = hwbase + wvpx + kg * 4;
#pragma unroll
    for (int nf = 0; nf < 4; ++nf) {
        size_t ob = ((size_t)(b * O + nf * 16 + ml)) * HXW + hwb;
        *(float4*)(out + ob) = __builtin_bit_cast(float4, acc[nf]);
    }
}

extern "C" void kernel_launch(void* const* d_in, const int* in_sizes, int n_in,
                              void* d_out, int out_size, void* d_ws, size_t ws_size,
                              hipStream_t stream) {
    const float* x      = (const float*)d_in[0];
    const float* offset = (const float*)d_in[1];
    const float* mask   = (const float*)d_in[2];
    const float* weight = (const float*)d_in[3];
    const float* bias   = (const float*)d_in[4];
    float* out = (float*)d_out;

    _Float16* wth = (_Float16*)d_ws;                              // 73728 B
    _Float16* xht = (_Float16*)((char*)d_ws + 73728);             // 8.39 MB
    size_t need = 73728 + (size_t)B * HXW * 64 * sizeof(_Float16);

    if (ws_size >= need) {
        int wth_blocks = (K * O * C + 255) / 256;                 // 144
        prep_kernel<<<XT_BLOCKS + wth_blocks, 256, 0, stream>>>(x, weight, xht, wth);
        mdcn_f16<<<1024, 256, 0, stream>>>(xht, offset, mask, wth, bias, out);
    } else {
        float* wt = (float*)d_ws;                                 // 147456 B (fallback)
        wt_kernel<<<(K * C * O + 255) / 256, 256, 0, stream>>>(weight, wt);
        mdcn_nchw<<<(B * HXW) / 256, 256, 0, stream>>>(x, offset, mask, wt, bias, out);
    }
}